// Round 13
// baseline (809.153 us; speedup 1.0000x reference)
//
#include <hip/hip_runtime.h>
#include <hip/hip_bf16.h>

#define DI __device__ __forceinline__

typedef short bf16x8 __attribute__((ext_vector_type(8)));
typedef float f32x4 __attribute__((ext_vector_type(4)));
typedef unsigned short u16;
typedef u16 u16x2 __attribute__((ext_vector_type(2)));
typedef u16 u16x4 __attribute__((ext_vector_type(4)));
typedef u16 u16x8 __attribute__((ext_vector_type(8)));

#define B_ 16
#define C_ 512
#define CR_ 64
#define H_ 96
#define HW_ 9216
#define K_ 512

DI float b2f(u16 u){ unsigned v = ((unsigned)u)<<16; float f; __builtin_memcpy(&f,&v,4); return f; }
DI u16 f2b(float f){ unsigned v; __builtin_memcpy(&v,&f,4); v += 0x7fff + ((v>>16)&1); return (u16)(v>>16); }

DI void gload16(const void* g, void* l){
  __builtin_amdgcn_global_load_lds((const __attribute__((address_space(1))) unsigned*)g,
                                   (__attribute__((address_space(3))) unsigned*)l, 16, 0, 0);
}

// ---------------- K0a: pack weights to bf16 Wcat[640][512], bias fp32 ----------------
__global__ __launch_bounds__(256) void k_pack(const float* __restrict__ Wq, const float* __restrict__ bq,
    const float* __restrict__ Wk, const float* __restrict__ bk,
    const float* __restrict__ Wv, const float* __restrict__ bv,
    u16* __restrict__ Wcat, float* __restrict__ bcat){
  int gid = blockIdx.x*256 + threadIdx.x;          // 0..327679
  int o = gid >> 9, c = gid & 511;
  float w = (o < 64) ? Wq[o*512 + c] : (o < 128) ? Wk[(o-64)*512 + c] : Wv[(o-128)*512 + c];
  Wcat[gid] = f2b(w);
  if (c == 0) bcat[o] = (o < 64) ? bq[o] : (o < 128) ? bk[o-64] : bv[o-128];
}

// ---------------- K0b: x (b,c,p) fp32 -> x_t (b,p,c) bf16, coalesced reads ----------------
__global__ __launch_bounds__(256) void k_xt(const float* __restrict__ x, u16* __restrict__ xt){
  int bx = blockIdx.x;
  int pt = bx % 144; int ct = (bx/144) & 7; int b = bx / (144*8);
  __shared__ u16 T[64*80];                         // T[p][c], pitch 80
  const float* xb = x + (size_t)b*C_*HW_ + (size_t)(ct*64)*HW_ + pt*64;
  for (int it = threadIdx.x; it < 1024; it += 256){
    int px4 = it & 15, r = it >> 4;                // 16 lanes cover a row's 64 p: 256B contiguous
    f32x4 f4 = *(const f32x4*)(xb + (size_t)r*HW_ + px4*4);
    #pragma unroll
    for (int e=0;e<4;++e) T[(px4*4 + e)*80 + r] = f2b(f4[e]);
  }
  __syncthreads();
  u16* xtb = xt + (size_t)b*HW_*K_ + (size_t)(pt*64)*K_ + ct*64;
  for (int it = threadIdx.x; it < 512; it += 256){
    int c8 = it & 7, p = it >> 3;
    u16x8 o;
    #pragma unroll
    for (int e=0;e<8;++e) o[e] = T[p*80 + c8*8 + e];
    *(u16x8*)(xtb + (size_t)p*K_ + c8*8) = o;
  }
}

// ---------------- K1: QKV GEMM. C[640 x 9216] = Wcat * x_t^T per batch ----------------
// 128x256 tile, BK=32, 8 waves (2x4), 2-phase double buffer in SAME 48KB LDS
// (As 2x8KB + Bs 2x16KB), one barrier per K-step with staging overlapped under
// compute, mt-fastest L2 ordering, slot-XOR epilogue (reuses Bs = 32KB).
// 64B-row swizzle: physical slot = logical ^ ((row>>1)&3); fragment reads 2-way (free).
__global__ __launch_bounds__(512) void k_qkv(const u16* __restrict__ Wcat, const float* __restrict__ bcat,
    const u16* __restrict__ xt, u16* __restrict__ q, u16* __restrict__ k, u16* __restrict__ v){
  int bx = blockIdx.x;
  int wg = (bx & 7)*360 + (bx >> 3);               // XCD swizzle: 2880 = 8*360 exact
  int mt = wg % 5; int rest = wg / 5; int nt = rest % 36; int b = rest / 36;
  __shared__ u16 As[2][128*32];                    // 2 x 8 KB
  __shared__ u16 Bs[2][256*32];                    // 2 x 16 KB; reused as C-tile (32 KB)
  int lane = threadIdx.x & 63, wid = threadIdx.x >> 6;
  int wr = wid >> 2, wc = wid & 3;                 // 2 x 4 wave grid
  const u16* xb = xt + (size_t)b*HW_*K_ + (size_t)nt*256*K_;
  const u16* Ab = Wcat + (size_t)mt*128*K_;

  // ---- per-thread staging geometry (constant across K-steps) ----
  // A: 1 issue/wave (8 KB total). dest base wid*1024; lane covers row wid*16+(lane>>2).
  int aRow = wid*16 + (lane>>2);
  int aSrc = aRow*K_ + (((lane&3) ^ ((aRow>>1)&3))<<3);
  // B: 2 issues/wave (16 KB total).
  int bRow0 = wid*32 + (lane>>2);
  int bRow1 = bRow0 + 16;
  int bSrc0 = bRow0*K_ + (((lane&3) ^ ((bRow0>>1)&3))<<3);
  int bSrc1 = bRow1*K_ + (((lane&3) ^ ((bRow1>>1)&3))<<3);
  // fragment byte offsets (within one buffer)
  int sl = lane >> 4;                              // logical 16B k-chunk 0..3
  int ofsA[4], ofsB[4];
  #pragma unroll
  for (int f=0; f<4; ++f){
    int ra = wr*64 + f*16 + (lane & 15);
    ofsA[f] = ra*64 + ((sl ^ ((ra>>1)&3))<<4);
    int rb = wc*64 + f*16 + (lane & 15);
    ofsB[f] = rb*64 + ((sl ^ ((rb>>1)&3))<<4);
  }

  f32x4 acc[4][4];
  #pragma unroll
  for (int i=0;i<4;++i)
    #pragma unroll
    for (int j=0;j<4;++j) acc[i][j] = (f32x4){0.f,0.f,0.f,0.f};

  // prologue: stage K-step 0 into buffer 0
  gload16(Ab + aSrc,  (char*)As[0] + wid*1024);
  gload16(xb + bSrc0, (char*)Bs[0] + wid*2048);
  gload16(xb + bSrc1, (char*)Bs[0] + wid*2048 + 1024);
  __syncthreads();                                 // vmcnt(0) drain + publish

  #pragma unroll
  for (int kt=0; kt<16; ++kt){
    int cur = kt & 1;
    if (kt < 15){                                  // issue next-step loads: fly under compute
      int k0 = (kt+1)*32;
      gload16(Ab + aSrc + k0,  (char*)As[cur^1] + wid*1024);
      gload16(xb + bSrc0 + k0, (char*)Bs[cur^1] + wid*2048);
      gload16(xb + bSrc1 + k0, (char*)Bs[cur^1] + wid*2048 + 1024);
    }
    bf16x8 af[4], bfr[4];
    #pragma unroll
    for (int f=0; f<4; ++f){
      af[f]  = *(const bf16x8*)((const char*)As[cur] + ofsA[f]);
      bfr[f] = *(const bf16x8*)((const char*)Bs[cur] + ofsB[f]);
    }
    #pragma unroll
    for (int fm=0; fm<4; ++fm)
      #pragma unroll
      for (int fn=0; fn<4; ++fn)
        acc[fm][fn] = __builtin_amdgcn_mfma_f32_16x16x32_bf16(af[fm], bfr[fn], acc[fm][fn], 0, 0, 0);
    __syncthreads();                               // drains next-step stage + guards reuse
  }

  // epilogue: restage C tile (128x256) through Bs (32 KB) in two 128-col halves.
  // slot-XOR: element col stored at 16B-slot (col>>3) ^ (((row>>2)&3)<<1)
  u16* Cs = (u16*)Bs;                              // 32 KB = 128x128 bf16
  int r4 = lane >> 4, cl = lane & 15;
  #pragma unroll
  for (int h=0; h<2; ++h){
    if (h) __syncthreads();                        // Cs free (prev stores done)
    if ((wc >> 1) == h){                           // waves owning this half
      #pragma unroll
      for (int fm=0; fm<4; ++fm)
        #pragma unroll
        for (int j=0; j<4; ++j){
          int row = wr*64 + fm*16 + r4*4 + j;
          float bias = bcat[mt*128 + row];
          int sx = ((row>>2)&3)<<1;
          #pragma unroll
          for (int fn=0; fn<4; ++fn){
            int col = (wc&1)*64 + fn*16 + cl;      // 0..127 within half
            Cs[row*128 + (((col>>3) ^ sx)<<3) + (col&7)] = f2b(acc[fm][fn][j] + bias);
          }
        }
    }
    __syncthreads();
    #pragma unroll
    for (int i=0; i<4; ++i){
      int chunk = i*512 + threadIdx.x;             // 2048 chunks of 16B
      int row = chunk >> 4, c8 = chunk & 15;
      int sx = ((row>>2)&3)<<1;
      u16x8 val = *(const u16x8*)&Cs[row*128 + (c8<<3)];
      int colb = c8 ^ sx;                          // actual column block in this slot
      int o = mt*128 + row;
      int n = nt*256 + h*128 + colb*8;
      u16* dst;
      if (o < 64)       dst = q + ((size_t)b*CR_ + o)*HW_ + n;
      else if (o < 128) dst = k + ((size_t)b*CR_ + (o-64))*HW_ + n;
      else              dst = v + ((size_t)b*C_ + (o-128))*HW_ + n;
      *(u16x8*)dst = val;
    }
  }
}

// ---------------- K2: per-image 96x96 transpose q,k,v -> qt,kt,vt (vectorized, swizzled) ----------------
__global__ __launch_bounds__(256) void k_tr(const u16* __restrict__ q, const u16* __restrict__ kk,
    const u16* __restrict__ v, u16* __restrict__ qt, u16* __restrict__ kt, u16* __restrict__ vt){
  int bx = blockIdx.x;
  int ch = bx % 640; int b = bx / 640;
  const u16* src; u16* dst;
  if (ch < 64)      { src = q  + ((size_t)b*CR_ + ch)*HW_;     dst = qt + ((size_t)b*CR_ + ch)*HW_; }
  else if (ch < 128){ src = kk + ((size_t)b*CR_ + ch-64)*HW_;  dst = kt + ((size_t)b*CR_ + ch-64)*HW_; }
  else              { src = v  + ((size_t)b*C_ + ch-128)*HW_;  dst = vt + ((size_t)b*C_ + ch-128)*HW_; }
  __shared__ u16 T[96*128];                        // T[w][h], 16 swizzled 16B slots per row
  for (int it = threadIdx.x; it < 1152; it += 256){
    int h = it / 12, c8 = it % 12;
    u16x8 v8 = *(const u16x8*)(src + h*96 + c8*8);
    int sp = (h >> 3) ^ (c8 & 7);                  // slot h>>3 swizzled by (w>>3)&7 = c8&7
    #pragma unroll
    for (int e = 0; e < 8; ++e){
      int w = c8*8 + e;
      T[w*128 + sp*8 + (h & 7)] = v8[e];
    }
  }
  __syncthreads();
  for (int it = threadIdx.x; it < 1152; it += 256){
    int w = it / 12, h8 = it % 12;
    int sp = h8 ^ ((w >> 3) & 7);
    u16x8 o = *(const u16x8*)&T[w*128 + sp*8];
    *(u16x8*)(dst + (size_t)w*96 + h8*8) = o;
  }
}

// ---------------- K3: scores (RAW, softmax folded into consumers) ----------------
__global__ __launch_bounds__(256) void k_scores(const u16* __restrict__ q, const u16* __restrict__ k,
    const u16* __restrict__ qt, const u16* __restrict__ kt, u16* __restrict__ att){
  int bx = blockIdx.x;
  int p = bx % 96; int b = (bx/96) & 15; int mode = bx / 1536;
  __shared__ float Qs[64*96];
  __shared__ float Ks[64*96];
  const u16* qsrc; const u16* ksrc;
  if (mode == 0){ qsrc = qt + (size_t)b*CR_*HW_ + p*96; ksrc = kt + (size_t)b*CR_*HW_ + p*96; }
  else          { qsrc = q  + (size_t)b*CR_*HW_ + p*96; ksrc = k  + (size_t)b*CR_*HW_ + p*96; }
  for (int u = threadIdx.x; u < 64*12; u += 256){
    int c = u / 12, ch = u % 12;
    u16x8 a = *(const u16x8*)(qsrc + (size_t)c*HW_ + ch*8);
    u16x8 d = *(const u16x8*)(ksrc + (size_t)c*HW_ + ch*8);
    #pragma unroll
    for (int e=0;e<8;++e){ Qs[c*96 + ch*8 + e] = b2f(a[e]); Ks[c*96 + ch*8 + e] = b2f(d[e]); }
  }
  __syncthreads();
  int ti = threadIdx.x >> 4, tj = threadIdx.x & 15;
  float acc[6][6];
  #pragma unroll
  for (int a2=0;a2<6;++a2)
    #pragma unroll
    for (int b2=0;b2<6;++b2) acc[a2][b2] = 0.f;
  for (int c=0;c<64;++c){
    float qv[6], kv[6];
    #pragma unroll
    for (int a2=0;a2<6;++a2){ qv[a2] = Qs[c*96 + ti + 16*a2]; kv[a2] = Ks[c*96 + tj + 16*a2]; }
    #pragma unroll
    for (int a2=0;a2<6;++a2)
      #pragma unroll
      for (int b2=0;b2<6;++b2) acc[a2][b2] += qv[a2]*kv[b2];
  }
  for (int a2=0;a2<6;++a2){
    int i = ti + 16*a2;
    for (int b2=0;b2<6;++b2){
      int j = tj + 16*b2;
      size_t idx = (mode==0) ? ((size_t)((b*96 + i)*96 + p))*192 + j
                             : ((size_t)((b*96 + p)*96 + i))*192 + 96 + j;
      att[idx] = f2b(acc[a2][b2]);
    }
  }
}

// ---------------- K5a: out_h per (b,w), IN PLACE over vt, softmax fused ----------------
__global__ __launch_bounds__(512) void k_outh(u16* vo, const u16* __restrict__ att){
  int bx = blockIdx.x; int w = bx % 96, b = bx / 96;
  __shared__ u16 Ah[96*104];
  int hw = threadIdx.x >> 5, sub = threadIdx.x & 31;
  for (int r0 = 0; r0 < 96; r0 += 16){
    int i = r0 + hw;
    const u16* rp = att + ((size_t)((b*96 + i)*96 + w))*192 + sub*6;
    u16x2 a2 = *(const u16x2*)rp, b2v = *(const u16x2*)(rp+2), c2 = *(const u16x2*)(rp+4);
    float v0=b2f(a2[0]),v1=b2f(a2[1]),v2=b2f(b2v[0]),v3=b2f(b2v[1]),v4=b2f(c2[0]),v5=b2f(c2[1]);
    float m = fmaxf(fmaxf(fmaxf(v0,v1),fmaxf(v2,v3)),fmaxf(v4,v5));
    #pragma unroll
    for (int off=16; off; off>>=1) m = fmaxf(m, __shfl_xor(m, off));
    float e0=__expf(v0-m),e1=__expf(v1-m),e2=__expf(v2-m),e3=__expf(v3-m),e4=__expf(v4-m),e5=__expf(v5-m);
    float s = ((e0+e1)+(e2+e3))+(e4+e5);
    #pragma unroll
    for (int off=16; off; off>>=1) s += __shfl_xor(s, off);
    float inv = 1.0f/s;
    if (sub < 16){                                 // j = sub*6..sub*6+5 < 96 (h-half)
      u16* d = &Ah[i*104 + sub*6];
      d[0]=f2b(e0*inv); d[1]=f2b(e1*inv); d[2]=f2b(e2*inv);
      d[3]=f2b(e3*inv); d[4]=f2b(e4*inv); d[5]=f2b(e5*inv);
    }
  }
  __syncthreads();
  int lane = threadIdx.x & 63, wid = threadIdx.x >> 6;
  int cl = lane & 15, r4 = lane >> 4;
  f32x4 acc[4][6];
  #pragma unroll
  for (int i=0;i<4;++i)
    #pragma unroll
    for (int j=0;j<6;++j) acc[i][j] = (f32x4){0.f,0.f,0.f,0.f};
  u16* vb = vo + (size_t)b*C_*HW_ + (size_t)w*96;
  #pragma unroll
  for (int kt=0; kt<3; ++kt){
    int kof = kt*32 + r4*8;
    bf16x8 a[4], bb[6];
    #pragma unroll
    for (int fm=0; fm<4; ++fm){
      int c = wid*64 + fm*16 + cl;
      a[fm] = *(const bf16x8*)(vb + (size_t)c*HW_ + kof);
    }
    #pragma unroll
    for (int fn=0; fn<6; ++fn)
      bb[fn] = *(const bf16x8*)&Ah[(fn*16 + cl)*104 + kof];
    #pragma unroll
    for (int fm=0; fm<4; ++fm)
      #pragma unroll
      for (int fn=0; fn<6; ++fn)
        acc[fm][fn] = __builtin_amdgcn_mfma_f32_16x16x32_bf16(a[fm], bb[fn], acc[fm][fn], 0, 0, 0);
  }
  for (int fm=0; fm<4; ++fm)
    for (int fn=0; fn<6; ++fn)
      for (int j=0;j<4;++j){
        int c = wid*64 + fm*16 + r4*4 + j;
        int i = fn*16 + cl;
        vb[(size_t)c*HW_ + i] = f2b(acc[fm][fn][j]);
      }
}

// ---------------- K5b: out_w per (b,h), IN PLACE over v, softmax fused ----------------
__global__ __launch_bounds__(512) void k_outw(u16* vo, const u16* __restrict__ att){
  int bx = blockIdx.x; int h = bx % 96, b = bx / 96;
  __shared__ u16 Aw[96*104];
  int hw = threadIdx.x >> 5, sub = threadIdx.x & 31;
  for (int r0 = 0; r0 < 96; r0 += 16){
    int i = r0 + hw;
    const u16* rp = att + ((size_t)((b*96 + h)*96 + i))*192 + sub*6;
    u16x2 a2 = *(const u16x2*)rp, b2v = *(const u16x2*)(rp+2), c2 = *(const u16x2*)(rp+4);
    float v0=b2f(a2[0]),v1=b2f(a2[1]),v2=b2f(b2v[0]),v3=b2f(b2v[1]),v4=b2f(c2[0]),v5=b2f(c2[1]);
    float m = fmaxf(fmaxf(fmaxf(v0,v1),fmaxf(v2,v3)),fmaxf(v4,v5));
    #pragma unroll
    for (int off=16; off; off>>=1) m = fmaxf(m, __shfl_xor(m, off));
    float e0=__expf(v0-m),e1=__expf(v1-m),e2=__expf(v2-m),e3=__expf(v3-m),e4=__expf(v4-m),e5=__expf(v5-m);
    float s = ((e0+e1)+(e2+e3))+(e4+e5);
    #pragma unroll
    for (int off=16; off; off>>=1) s += __shfl_xor(s, off);
    float inv = 1.0f/s;
    if (sub >= 16){                                // j = sub*6-96 .. +5 (w-half)
      u16* d = &Aw[i*104 + sub*6 - 96];
      d[0]=f2b(e0*inv); d[1]=f2b(e1*inv); d[2]=f2b(e2*inv);
      d[3]=f2b(e3*inv); d[4]=f2b(e4*inv); d[5]=f2b(e5*inv);
    }
  }
  __syncthreads();
  int lane = threadIdx.x & 63, wid = threadIdx.x >> 6;
  int cl = lane & 15, r4 = lane >> 4;
  f32x4 acc[4][6];
  #pragma unroll
  for (int i=0;i<4;++i)
    #pragma unroll
    for (int j=0;j<6;++j) acc[i][j] = (f32x4){0.f,0.f,0.f,0.f};
  u16* vb = vo + (size_t)b*C_*HW_ + (size_t)h*96;
  #pragma unroll
  for (int kt=0; kt<3; ++kt){
    int kof = kt*32 + r4*8;
    bf16x8 a[4], bb[6];
    #pragma unroll
    for (int fm=0; fm<4; ++fm){
      int c = wid*64 + fm*16 + cl;
      a[fm] = *(const bf16x8*)(vb + (size_t)c*HW_ + kof);
    }
    #pragma unroll
    for (int fn=0; fn<6; ++fn)
      bb[fn] = *(const bf16x8*)&Aw[(fn*16 + cl)*104 + kof];
    #pragma unroll
    for (int fm=0; fm<4; ++fm)
      #pragma unroll
      for (int fn=0; fn<6; ++fn)
        acc[fm][fn] = __builtin_amdgcn_mfma_f32_16x16x32_bf16(a[fm], bb[fn], acc[fm][fn], 0, 0, 0);
  }
  for (int fm=0; fm<4; ++fm)
    for (int fn=0; fn<6; ++fn)
      for (int j=0;j<4;++j){
        int c = wid*64 + fm*16 + r4*4 + j;
        int i = fn*16 + cl;
        vb[(size_t)c*HW_ + i] = f2b(acc[fm][fn][j]);
      }
}

// ---------------- K6: out = gamma*(oh^T + ow) + x. nontemporal out stores ----------------
__global__ __launch_bounds__(256) void k_final(const u16* oh, const u16* ow,
    const float* __restrict__ x, const float* __restrict__ gp, float* __restrict__ out){
  int bx = blockIdx.x; int c = bx & 511; int b = bx >> 9;
  size_t base = ((size_t)b*C_ + c)*HW_;
  const u16* ohc = oh + base;
  const u16* owc = ow + base;
  __shared__ u16 T[96*100];                        // T[i][w], pitch 100 u16 (200 B)
  for (int it = threadIdx.x; it < 288; it += 256){
    int w4 = it % 24, i8 = it / 24;                // 4-w-row batch, i-chunk of 8
    const u16* src = ohc + (w4*4)*96 + i8*8;
    u16x8 r0 = *(const u16x8*)(src);
    u16x8 r1 = *(const u16x8*)(src + 96);
    u16x8 r2 = *(const u16x8*)(src + 192);
    u16x8 r3 = *(const u16x8*)(src + 288);
    #pragma unroll
    for (int e = 0; e < 8; ++e){
      u16x4 t = {r0[e], r1[e], r2[e], r3[e]};      // {oh[w..w+3][i]}
      *(u16x4*)&T[(i8*8 + e)*100 + w4*4] = t;
    }
  }
  __syncthreads();
  float g = gp[0];
  for (int it = threadIdx.x; it < 2304; it += 256){
    int i = it / 24, w4 = it % 24; int w = w4*4;
    u16x4 t4 = *(const u16x4*)&T[i*100 + w4*4];
    u16x4 o4 = *(const u16x4*)(owc + i*96 + w);
    f32x4 x4 = *(const f32x4*)(x + base + i*96 + w);
    f32x4 r;
    #pragma unroll
    for (int e=0;e<4;++e) r[e] = g*(b2f(t4[e]) + b2f(o4[e])) + x4[e];
    __builtin_nontemporal_store(r, (f32x4*)(out + base + i*96 + w));
  }
}

extern "C" void kernel_launch(void* const* d_in, const int* in_sizes, int n_in,
                              void* d_out, int out_size, void* d_ws, size_t ws_size,
                              hipStream_t stream) {
  (void)in_sizes; (void)n_in; (void)out_size; (void)ws_size;
  const float* x  = (const float*)d_in[0];
  const float* Wq = (const float*)d_in[1];
  const float* bq = (const float*)d_in[2];
  const float* Wk = (const float*)d_in[3];
  const float* bk = (const float*)d_in[4];
  const float* Wv = (const float*)d_in[5];
  const float* bv = (const float*)d_in[6];
  const float* gm = (const float*)d_in[7];
  float* out = (float*)d_out;
  char* ws = (char*)d_ws;

  // workspace layout (total 434,769,920 B)
  u16*  Wcat = (u16*)(ws);                    //    655,360
  float* bcat= (float*)(ws + 655360);         //      4,096 (pad)
  u16*  q    = (u16*)(ws + 659456);           // 18,874,368
  u16*  k    = (u16*)(ws + 19533824);         // 18,874,368
  u16*  qt   = (u16*)(ws + 38408192);         // 18,874,368
  u16*  kt   = (u16*)(ws + 57282560);         // 18,874,368
  u16*  v    = (u16*)(ws + 76156928);         // 150,994,944  (becomes ow in place)
  u16*  att  = (u16*)(ws + 227151872);        // 56,623,104   (raw scores, read-only after k_scores)
  u16*  vt   = (u16*)(ws + 283774976);        // 150,994,944  (becomes oh in place)
  // d_out first half doubles as x_t scratch (dead after k_qkv).
  u16*  xt   = (u16*)d_out;

  k_pack   <<<1280, 256, 0, stream>>>(Wq,bq,Wk,bk,Wv,bv,Wcat,bcat);
  k_xt     <<<18432,256, 0, stream>>>(x, xt);
  k_qkv    <<<2880, 512, 0, stream>>>(Wcat,bcat,xt,q,k,v);
  k_tr     <<<10240,256, 0, stream>>>(q,k,v,qt,kt,vt);
  k_scores <<<3072, 256, 0, stream>>>(q,k,qt,kt,att);
  k_outh   <<<1536, 512, 0, stream>>>(vt,att);
  k_outw   <<<1536, 512, 0, stream>>>(v,att);
  k_final  <<<8192, 256, 0, stream>>>(vt,v,x,gm,out);
}

// Round 14
// 728.928 us; speedup vs baseline: 1.1101x; 1.1101x over previous
//
#include <hip/hip_runtime.h>
#include <hip/hip_bf16.h>

#define DI __device__ __forceinline__

typedef short bf16x8 __attribute__((ext_vector_type(8)));
typedef float f32x4 __attribute__((ext_vector_type(4)));
typedef unsigned short u16;
typedef u16 u16x2 __attribute__((ext_vector_type(2)));
typedef u16 u16x4 __attribute__((ext_vector_type(4)));
typedef u16 u16x8 __attribute__((ext_vector_type(8)));

#define B_ 16
#define C_ 512
#define CR_ 64
#define H_ 96
#define HW_ 9216
#define K_ 512

DI float b2f(u16 u){ unsigned v = ((unsigned)u)<<16; float f; __builtin_memcpy(&f,&v,4); return f; }
DI u16 f2b(float f){ unsigned v; __builtin_memcpy(&v,&f,4); v += 0x7fff + ((v>>16)&1); return (u16)(v>>16); }

DI void gload16(const void* g, void* l){
  __builtin_amdgcn_global_load_lds((const __attribute__((address_space(1))) unsigned*)g,
                                   (__attribute__((address_space(3))) unsigned*)l, 16, 0, 0);
}

// ---------------- K0a: pack weights to bf16 Wcat[640][512], bias fp32 ----------------
__global__ __launch_bounds__(256) void k_pack(const float* __restrict__ Wq, const float* __restrict__ bq,
    const float* __restrict__ Wk, const float* __restrict__ bk,
    const float* __restrict__ Wv, const float* __restrict__ bv,
    u16* __restrict__ Wcat, float* __restrict__ bcat){
  int gid = blockIdx.x*256 + threadIdx.x;          // 0..327679
  int o = gid >> 9, c = gid & 511;
  float w = (o < 64) ? Wq[o*512 + c] : (o < 128) ? Wk[(o-64)*512 + c] : Wv[(o-128)*512 + c];
  Wcat[gid] = f2b(w);
  if (c == 0) bcat[o] = (o < 64) ? bq[o] : (o < 128) ? bk[o-64] : bv[o-128];
}

// ---------------- K0b: x (b,c,p) fp32 -> x_t (b,p,c) bf16 ----------------
// c-block XOR swizzle by (p>>2)&7 breaks the pitch-80 16-way write conflict
// (p and p+4 rows collide: 160 dwords = 0 mod 32); reads stay u16x8 aligned.
__global__ __launch_bounds__(256) void k_xt(const float* __restrict__ x, u16* __restrict__ xt){
  int bx = blockIdx.x;
  int pt = bx % 144; int ct = (bx/144) & 7; int b = bx / (144*8);
  __shared__ u16 T[64*80];                         // T[p][c], pitch 80, swizzled c-blocks
  const float* xb = x + (size_t)b*C_*HW_ + (size_t)(ct*64)*HW_ + pt*64;
  for (int it = threadIdx.x; it < 1024; it += 256){
    int px4 = it & 15, r = it >> 4;                // r = c-row, px4 = p-chunk (4 floats)
    f32x4 f4 = *(const f32x4*)(xb + (size_t)r*HW_ + px4*4);
    #pragma unroll
    for (int e=0;e<4;++e){
      int p = px4*4 + e;
      T[p*80 + (r ^ (((p>>2)&7)<<3))] = f2b(f4[e]);
    }
  }
  __syncthreads();
  u16* xtb = xt + (size_t)b*HW_*K_ + (size_t)(pt*64)*K_ + ct*64;
  for (int it = threadIdx.x; it < 512; it += 256){
    int c8 = it & 7, p = it >> 3;
    u16x8 o = *(const u16x8*)&T[p*80 + ((c8 ^ ((p>>2)&7))<<3)];
    *(u16x8*)(xtb + (size_t)p*K_ + c8*8) = o;
  }
}

// ---------------- K1: QKV GEMM. C[640 x 9216] = Wcat * x_t^T per batch ----------------
// ROUND-8 PROVEN STRUCTURE (locked): 128x256 tile, BK=64, 8 waves (2x4),
// single 48KB buffer, 2 barriers/K-step, mt-fastest L2 ordering,
// slot-XOR epilogue restaged in two 32KB halves. 175 us, 0 bank conflicts.
// Do NOT re-attempt double-buffer/persistence here (r4/r6/r13 all regressed).
__global__ __launch_bounds__(512) void k_qkv(const u16* __restrict__ Wcat, const float* __restrict__ bcat,
    const u16* __restrict__ xt, u16* __restrict__ q, u16* __restrict__ k, u16* __restrict__ v){
  int bx = blockIdx.x;
  int wg = (bx & 7)*360 + (bx >> 3);               // XCD swizzle: 2880 = 8*360 exact
  int mt = wg % 5; int rest = wg / 5; int nt = rest % 36; int b = rest / 36;
  __shared__ u16 As[128*64];                       // 16 KB
  __shared__ u16 Bs[256*64];                       // 32 KB; reused as C-tile halves
  int lane = threadIdx.x & 63, wid = threadIdx.x >> 6;
  int wr = wid >> 2, wc = wid & 3;                 // 2 x 4 wave grid
  const u16* xb = xt + (size_t)b*HW_*K_ + (size_t)nt*256*K_;
  const u16* Ab = Wcat + (size_t)mt*128*K_;

  f32x4 acc[4][4];
  #pragma unroll
  for (int i=0;i<4;++i)
    #pragma unroll
    for (int j=0;j<4;++j) acc[i][j] = (f32x4){0.f,0.f,0.f,0.f};

  for (int kt=0; kt<8; ++kt){
    int k0 = kt*64;
    __syncthreads();
    // A: 16 issues of 1KB -> 2 per wave. B: 32 issues -> 4 per wave.
    #pragma unroll
    for (int i=0;i<2;++i){
      int dest = ((wid*2 + i)<<10);
      int byteL = dest + (lane<<4);
      int row = byteL >> 7;                        // 128B per LDS row (64 bf16)
      int slog = ((byteL >> 4) & 7) ^ (row & 7);
      gload16(Ab + (size_t)row*K_ + (k0 + slog*8), (char*)As + dest);
    }
    #pragma unroll
    for (int i=0;i<4;++i){
      int dest = ((wid*4 + i)<<10);
      int byteL = dest + (lane<<4);
      int row = byteL >> 7;
      int slog = ((byteL >> 4) & 7) ^ (row & 7);
      gload16(xb + (size_t)row*K_ + (k0 + slog*8), (char*)Bs + dest);
    }
    __syncthreads();
    bf16x8 af[4][2], bfr[4][2];
    #pragma unroll
    for (int f=0; f<4; ++f){
      #pragma unroll
      for (int kk=0; kk<2; ++kk){
        int sl = kk*4 + (lane >> 4);
        int ra = wr*64 + f*16 + (lane & 15);
        af[f][kk]  = *(const bf16x8*)((const char*)As + ra*128 + ((sl ^ (ra & 7))<<4));
        int rb = wc*64 + f*16 + (lane & 15);
        bfr[f][kk] = *(const bf16x8*)((const char*)Bs + rb*128 + ((sl ^ (rb & 7))<<4));
      }
    }
    #pragma unroll
    for (int fm=0; fm<4; ++fm)
      #pragma unroll
      for (int fn=0; fn<4; ++fn)
        #pragma unroll
        for (int kk=0; kk<2; ++kk)
          acc[fm][fn] = __builtin_amdgcn_mfma_f32_16x16x32_bf16(af[fm][kk], bfr[fn][kk], acc[fm][fn], 0, 0, 0);
  }

  // epilogue: restage C tile (128x256) through Bs in two 128-col halves.
  // slot-XOR: element col stored at 16B-slot (col>>3) ^ (((row>>2)&3)<<1)
  u16* Cs = Bs;                                    // 32 KB = 128x128 bf16
  int r4 = lane >> 4, cl = lane & 15;
  #pragma unroll
  for (int h=0; h<2; ++h){
    __syncthreads();                               // Cs free (ds_reads / prev stores done)
    if ((wc >> 1) == h){                           // waves owning this half
      #pragma unroll
      for (int fm=0; fm<4; ++fm)
        #pragma unroll
        for (int j=0; j<4; ++j){
          int row = wr*64 + fm*16 + r4*4 + j;
          float bias = bcat[mt*128 + row];
          int sx = ((row>>2)&3)<<1;
          #pragma unroll
          for (int fn=0; fn<4; ++fn){
            int col = (wc&1)*64 + fn*16 + cl;      // 0..127 within half
            Cs[row*128 + (((col>>3) ^ sx)<<3) + (col&7)] = f2b(acc[fm][fn][j] + bias);
          }
        }
    }
    __syncthreads();
    #pragma unroll
    for (int i=0; i<4; ++i){
      int chunk = i*512 + threadIdx.x;             // 2048 chunks of 16B
      int row = chunk >> 4, c8 = chunk & 15;
      int sx = ((row>>2)&3)<<1;
      u16x8 val = *(const u16x8*)&Cs[row*128 + (c8<<3)];
      int colb = c8 ^ sx;                          // actual column block in this slot
      int o = mt*128 + row;
      int n = nt*256 + h*128 + colb*8;
      u16* dst;
      if (o < 64)       dst = q + ((size_t)b*CR_ + o)*HW_ + n;
      else if (o < 128) dst = k + ((size_t)b*CR_ + (o-64))*HW_ + n;
      else              dst = v + ((size_t)b*C_ + (o-128))*HW_ + n;
      *(u16x8*)dst = val;
    }
  }
}

// ---------------- K2: per-image 96x96 transpose q,k,v -> qt,kt,vt (vectorized, swizzled) ----------------
__global__ __launch_bounds__(256) void k_tr(const u16* __restrict__ q, const u16* __restrict__ kk,
    const u16* __restrict__ v, u16* __restrict__ qt, u16* __restrict__ kt, u16* __restrict__ vt){
  int bx = blockIdx.x;
  int ch = bx % 640; int b = bx / 640;
  const u16* src; u16* dst;
  if (ch < 64)      { src = q  + ((size_t)b*CR_ + ch)*HW_;     dst = qt + ((size_t)b*CR_ + ch)*HW_; }
  else if (ch < 128){ src = kk + ((size_t)b*CR_ + ch-64)*HW_;  dst = kt + ((size_t)b*CR_ + ch-64)*HW_; }
  else              { src = v  + ((size_t)b*C_ + ch-128)*HW_;  dst = vt + ((size_t)b*C_ + ch-128)*HW_; }
  __shared__ u16 T[96*128];                        // T[w][h], 16 swizzled 16B slots per row
  for (int it = threadIdx.x; it < 1152; it += 256){
    int h = it / 12, c8 = it % 12;
    u16x8 v8 = *(const u16x8*)(src + h*96 + c8*8);
    int sp = (h >> 3) ^ (c8 & 7);                  // slot h>>3 swizzled by (w>>3)&7 = c8&7
    #pragma unroll
    for (int e = 0; e < 8; ++e){
      int w = c8*8 + e;
      T[w*128 + sp*8 + (h & 7)] = v8[e];
    }
  }
  __syncthreads();
  for (int it = threadIdx.x; it < 1152; it += 256){
    int w = it / 12, h8 = it % 12;
    int sp = h8 ^ ((w >> 3) & 7);
    u16x8 o = *(const u16x8*)&T[w*128 + sp*8];
    *(u16x8*)(dst + (size_t)w*96 + h8*8) = o;
  }
}

// ---------------- K3: scores (RAW, softmax folded into consumers) ----------------
__global__ __launch_bounds__(256) void k_scores(const u16* __restrict__ q, const u16* __restrict__ k,
    const u16* __restrict__ qt, const u16* __restrict__ kt, u16* __restrict__ att){
  int bx = blockIdx.x;
  int p = bx % 96; int b = (bx/96) & 15; int mode = bx / 1536;
  __shared__ float Qs[64*96];
  __shared__ float Ks[64*96];
  const u16* qsrc; const u16* ksrc;
  if (mode == 0){ qsrc = qt + (size_t)b*CR_*HW_ + p*96; ksrc = kt + (size_t)b*CR_*HW_ + p*96; }
  else          { qsrc = q  + (size_t)b*CR_*HW_ + p*96; ksrc = k  + (size_t)b*CR_*HW_ + p*96; }
  for (int u = threadIdx.x; u < 64*12; u += 256){
    int c = u / 12, ch = u % 12;
    u16x8 a = *(const u16x8*)(qsrc + (size_t)c*HW_ + ch*8);
    u16x8 d = *(const u16x8*)(ksrc + (size_t)c*HW_ + ch*8);
    #pragma unroll
    for (int e=0;e<8;++e){ Qs[c*96 + ch*8 + e] = b2f(a[e]); Ks[c*96 + ch*8 + e] = b2f(d[e]); }
  }
  __syncthreads();
  int ti = threadIdx.x >> 4, tj = threadIdx.x & 15;
  float acc[6][6];
  #pragma unroll
  for (int a2=0;a2<6;++a2)
    #pragma unroll
    for (int b2=0;b2<6;++b2) acc[a2][b2] = 0.f;
  for (int c=0;c<64;++c){
    float qv[6], kv[6];
    #pragma unroll
    for (int a2=0;a2<6;++a2){ qv[a2] = Qs[c*96 + ti + 16*a2]; kv[a2] = Ks[c*96 + tj + 16*a2]; }
    #pragma unroll
    for (int a2=0;a2<6;++a2)
      #pragma unroll
      for (int b2=0;b2<6;++b2) acc[a2][b2] += qv[a2]*kv[b2];
  }
  for (int a2=0;a2<6;++a2){
    int i = ti + 16*a2;
    for (int b2=0;b2<6;++b2){
      int j = tj + 16*b2;
      size_t idx = (mode==0) ? ((size_t)((b*96 + i)*96 + p))*192 + j
                             : ((size_t)((b*96 + p)*96 + i))*192 + 96 + j;
      att[idx] = f2b(acc[a2][b2]);
    }
  }
}

// ---------------- K5a: out_h per (b,w), IN PLACE over vt, softmax fused ----------------
__global__ __launch_bounds__(512) void k_outh(u16* vo, const u16* __restrict__ att){
  int bx = blockIdx.x; int w = bx % 96, b = bx / 96;
  __shared__ u16 Ah[96*104];
  int hw = threadIdx.x >> 5, sub = threadIdx.x & 31;
  for (int r0 = 0; r0 < 96; r0 += 16){
    int i = r0 + hw;
    const u16* rp = att + ((size_t)((b*96 + i)*96 + w))*192 + sub*6;
    u16x2 a2 = *(const u16x2*)rp, b2v = *(const u16x2*)(rp+2), c2 = *(const u16x2*)(rp+4);
    float v0=b2f(a2[0]),v1=b2f(a2[1]),v2=b2f(b2v[0]),v3=b2f(b2v[1]),v4=b2f(c2[0]),v5=b2f(c2[1]);
    float m = fmaxf(fmaxf(fmaxf(v0,v1),fmaxf(v2,v3)),fmaxf(v4,v5));
    #pragma unroll
    for (int off=16; off; off>>=1) m = fmaxf(m, __shfl_xor(m, off));
    float e0=__expf(v0-m),e1=__expf(v1-m),e2=__expf(v2-m),e3=__expf(v3-m),e4=__expf(v4-m),e5=__expf(v5-m);
    float s = ((e0+e1)+(e2+e3))+(e4+e5);
    #pragma unroll
    for (int off=16; off; off>>=1) s += __shfl_xor(s, off);
    float inv = 1.0f/s;
    if (sub < 16){                                 // j = sub*6..sub*6+5 < 96 (h-half)
      u16* d = &Ah[i*104 + sub*6];
      d[0]=f2b(e0*inv); d[1]=f2b(e1*inv); d[2]=f2b(e2*inv);
      d[3]=f2b(e3*inv); d[4]=f2b(e4*inv); d[5]=f2b(e5*inv);
    }
  }
  __syncthreads();
  int lane = threadIdx.x & 63, wid = threadIdx.x >> 6;
  int cl = lane & 15, r4 = lane >> 4;
  f32x4 acc[4][6];
  #pragma unroll
  for (int i=0;i<4;++i)
    #pragma unroll
    for (int j=0;j<6;++j) acc[i][j] = (f32x4){0.f,0.f,0.f,0.f};
  u16* vb = vo + (size_t)b*C_*HW_ + (size_t)w*96;
  #pragma unroll
  for (int kt=0; kt<3; ++kt){
    int kof = kt*32 + r4*8;
    bf16x8 a[4], bb[6];
    #pragma unroll
    for (int fm=0; fm<4; ++fm){
      int c = wid*64 + fm*16 + cl;
      a[fm] = *(const bf16x8*)(vb + (size_t)c*HW_ + kof);
    }
    #pragma unroll
    for (int fn=0; fn<6; ++fn)
      bb[fn] = *(const bf16x8*)&Ah[(fn*16 + cl)*104 + kof];
    #pragma unroll
    for (int fm=0; fm<4; ++fm)
      #pragma unroll
      for (int fn=0; fn<6; ++fn)
        acc[fm][fn] = __builtin_amdgcn_mfma_f32_16x16x32_bf16(a[fm], bb[fn], acc[fm][fn], 0, 0, 0);
  }
  for (int fm=0; fm<4; ++fm)
    for (int fn=0; fn<6; ++fn)
      for (int j=0;j<4;++j){
        int c = wid*64 + fm*16 + r4*4 + j;
        int i = fn*16 + cl;
        vb[(size_t)c*HW_ + i] = f2b(acc[fm][fn][j]);
      }
}

// ---------------- K5b: out_w per (b,h), IN PLACE over v, softmax fused ----------------
__global__ __launch_bounds__(512) void k_outw(u16* vo, const u16* __restrict__ att){
  int bx = blockIdx.x; int h = bx % 96, b = bx / 96;
  __shared__ u16 Aw[96*104];
  int hw = threadIdx.x >> 5, sub = threadIdx.x & 31;
  for (int r0 = 0; r0 < 96; r0 += 16){
    int i = r0 + hw;
    const u16* rp = att + ((size_t)((b*96 + h)*96 + i))*192 + sub*6;
    u16x2 a2 = *(const u16x2*)rp, b2v = *(const u16x2*)(rp+2), c2 = *(const u16x2*)(rp+4);
    float v0=b2f(a2[0]),v1=b2f(a2[1]),v2=b2f(b2v[0]),v3=b2f(b2v[1]),v4=b2f(c2[0]),v5=b2f(c2[1]);
    float m = fmaxf(fmaxf(fmaxf(v0,v1),fmaxf(v2,v3)),fmaxf(v4,v5));
    #pragma unroll
    for (int off=16; off; off>>=1) m = fmaxf(m, __shfl_xor(m, off));
    float e0=__expf(v0-m),e1=__expf(v1-m),e2=__expf(v2-m),e3=__expf(v3-m),e4=__expf(v4-m),e5=__expf(v5-m);
    float s = ((e0+e1)+(e2+e3))+(e4+e5);
    #pragma unroll
    for (int off=16; off; off>>=1) s += __shfl_xor(s, off);
    float inv = 1.0f/s;
    if (sub >= 16){                                // j = sub*6-96 .. +5 (w-half)
      u16* d = &Aw[i*104 + sub*6 - 96];
      d[0]=f2b(e0*inv); d[1]=f2b(e1*inv); d[2]=f2b(e2*inv);
      d[3]=f2b(e3*inv); d[4]=f2b(e4*inv); d[5]=f2b(e5*inv);
    }
  }
  __syncthreads();
  int lane = threadIdx.x & 63, wid = threadIdx.x >> 6;
  int cl = lane & 15, r4 = lane >> 4;
  f32x4 acc[4][6];
  #pragma unroll
  for (int i=0;i<4;++i)
    #pragma unroll
    for (int j=0;j<6;++j) acc[i][j] = (f32x4){0.f,0.f,0.f,0.f};
  u16* vb = vo + (size_t)b*C_*HW_ + (size_t)h*96;
  #pragma unroll
  for (int kt=0; kt<3; ++kt){
    int kof = kt*32 + r4*8;
    bf16x8 a[4], bb[6];
    #pragma unroll
    for (int fm=0; fm<4; ++fm){
      int c = wid*64 + fm*16 + cl;
      a[fm] = *(const bf16x8*)(vb + (size_t)c*HW_ + kof);
    }
    #pragma unroll
    for (int fn=0; fn<6; ++fn)
      bb[fn] = *(const bf16x8*)&Aw[(fn*16 + cl)*104 + kof];
    #pragma unroll
    for (int fm=0; fm<4; ++fm)
      #pragma unroll
      for (int fn=0; fn<6; ++fn)
        acc[fm][fn] = __builtin_amdgcn_mfma_f32_16x16x32_bf16(a[fm], bb[fn], acc[fm][fn], 0, 0, 0);
  }
  for (int fm=0; fm<4; ++fm)
    for (int fn=0; fn<6; ++fn)
      for (int j=0;j<4;++j){
        int c = wid*64 + fm*16 + r4*4 + j;
        int i = fn*16 + cl;
        vb[(size_t)c*HW_ + i] = f2b(acc[fm][fn][j]);
      }
}

// ---------------- K6: out = gamma*(oh^T + ow) + x. nontemporal out stores ----------------
__global__ __launch_bounds__(256) void k_final(const u16* oh, const u16* ow,
    const float* __restrict__ x, const float* __restrict__ gp, float* __restrict__ out){
  int bx = blockIdx.x; int c = bx & 511; int b = bx >> 9;
  size_t base = ((size_t)b*C_ + c)*HW_;
  const u16* ohc = oh + base;
  const u16* owc = ow + base;
  __shared__ u16 T[96*100];                        // T[i][w], pitch 100 u16 (200 B)
  for (int it = threadIdx.x; it < 288; it += 256){
    int w4 = it % 24, i8 = it / 24;                // 4-w-row batch, i-chunk of 8
    const u16* src = ohc + (w4*4)*96 + i8*8;
    u16x8 r0 = *(const u16x8*)(src);
    u16x8 r1 = *(const u16x8*)(src + 96);
    u16x8 r2 = *(const u16x8*)(src + 192);
    u16x8 r3 = *(const u16x8*)(src + 288);
    #pragma unroll
    for (int e = 0; e < 8; ++e){
      u16x4 t = {r0[e], r1[e], r2[e], r3[e]};      // {oh[w..w+3][i]}
      *(u16x4*)&T[(i8*8 + e)*100 + w4*4] = t;
    }
  }
  __syncthreads();
  float g = gp[0];
  for (int it = threadIdx.x; it < 2304; it += 256){
    int i = it / 24, w4 = it % 24; int w = w4*4;
    u16x4 t4 = *(const u16x4*)&T[i*100 + w4*4];
    u16x4 o4 = *(const u16x4*)(owc + i*96 + w);
    f32x4 x4 = *(const f32x4*)(x + base + i*96 + w);
    f32x4 r;
    #pragma unroll
    for (int e=0;e<4;++e) r[e] = g*(b2f(t4[e]) + b2f(o4[e])) + x4[e];
    __builtin_nontemporal_store(r, (f32x4*)(out + base + i*96 + w));
  }
}

extern "C" void kernel_launch(void* const* d_in, const int* in_sizes, int n_in,
                              void* d_out, int out_size, void* d_ws, size_t ws_size,
                              hipStream_t stream) {
  (void)in_sizes; (void)n_in; (void)out_size; (void)ws_size;
  const float* x  = (const float*)d_in[0];
  const float* Wq = (const float*)d_in[1];
  const float* bq = (const float*)d_in[2];
  const float* Wk = (const float*)d_in[3];
  const float* bk = (const float*)d_in[4];
  const float* Wv = (const float*)d_in[5];
  const float* bv = (const float*)d_in[6];
  const float* gm = (const float*)d_in[7];
  float* out = (float*)d_out;
  char* ws = (char*)d_ws;

  // workspace layout (total 434,769,920 B)
  u16*  Wcat = (u16*)(ws);                    //    655,360
  float* bcat= (float*)(ws + 655360);         //      4,096 (pad)
  u16*  q    = (u16*)(ws + 659456);           // 18,874,368
  u16*  k    = (u16*)(ws + 19533824);         // 18,874,368
  u16*  qt   = (u16*)(ws + 38408192);         // 18,874,368
  u16*  kt   = (u16*)(ws + 57282560);         // 18,874,368
  u16*  v    = (u16*)(ws + 76156928);         // 150,994,944  (becomes ow in place)
  u16*  att  = (u16*)(ws + 227151872);        // 56,623,104   (raw scores, read-only after k_scores)
  u16*  vt   = (u16*)(ws + 283774976);        // 150,994,944  (becomes oh in place)
  // d_out first half doubles as x_t scratch (dead after k_qkv).
  u16*  xt   = (u16*)d_out;

  k_pack   <<<1280, 256, 0, stream>>>(Wq,bq,Wk,bk,Wv,bv,Wcat,bcat);
  k_xt     <<<18432,256, 0, stream>>>(x, xt);
  k_qkv    <<<2880, 512, 0, stream>>>(Wcat,bcat,xt,q,k,v);
  k_tr     <<<10240,256, 0, stream>>>(q,k,v,qt,kt,vt);
  k_scores <<<3072, 256, 0, stream>>>(q,k,qt,kt,att);
  k_outh   <<<1536, 512, 0, stream>>>(vt,att);
  k_outw   <<<1536, 512, 0, stream>>>(v,att);
  k_final  <<<8192, 256, 0, stream>>>(vt,v,x,gm,out);
}